// Round 8
// baseline (111.811 us; speedup 1.0000x reference)
//
#include <hip/hip_runtime.h>

// Problem constants
static constexpr int NQ    = 12;
static constexpr int DEPTH = 4;
static constexpr int LAT   = 512;
static constexpr int FAST  = DEPTH * NQ;   // 48
static constexpr float DECAY = 0.9f;
static constexpr int PITCH = 66;           // even (b64 writes), 2-way bank alias = free

using v2f = __attribute__((ext_vector_type(2))) float;

// One wave = one batch element; block = one wave (wave-synchronous, NO fences:
// per-wave DS ops execute in order in the LDS pipe; the compiler's conservative
// alias analysis inserts minimal fine-grained lgkmcnt waits before first use).
//
// L orientation: i = (lane<<6) | r   (wires 0..5 lane bits, 6..11 reg bits)
// T orientation: i = (r<<6) | lane
// Layer = RY(12) ∘ CNOT-chain(0..10). sigma^-1: bit_p = j_p ^ j_{p+1}.
// Pass 1 folds sigma + L->T into read addressing -> wires 0..5 become register
// butterflies; Pass 2 transposes back -> wires 6..11 register butterflies.
// RYs on distinct wires commute, so within each pass we butterfly strides
// 16,8,4,2,1 (lower half first, then upper) and stride 32 LAST, letting
// butterflies on the lower half overlap the upper half's LDS reads.

// packed butterfly, stride S in {2,4,8,16}, restricted to [B, B+32)
template<int S, int B>
__device__ __forceinline__ void bfly_half(float (&v)[64], float c, float s) {
    v2f c2 = {c, c}, s2 = {s, s};
    #pragma unroll
    for (int r0 = B; r0 < B + 32; r0 += 2) {
        if ((r0 & S) == 0) {
            v2f a = {v[r0],     v[r0 + 1]};
            v2f b = {v[r0 + S], v[r0 + S + 1]};
            v2f na = c2 * a - s2 * b;
            v2f nb = s2 * a + c2 * b;
            v[r0]         = na.x;  v[r0 + 1]     = na.y;
            v[r0 + S]     = nb.x;  v[r0 + S + 1] = nb.y;
        }
    }
}

// stride-1 butterfly (pair inside adjacent regs) on [B, B+32)
template<int B>
__device__ __forceinline__ void bfly1_half(float (&v)[64], float c, float s) {
    v2f cs = {c, s}, nsc = {-s, c};
    #pragma unroll
    for (int r0 = B; r0 < B + 32; r0 += 2) {
        float a = v[r0], b = v[r0 + 1];
        v2f aa = {a, a}, bb = {b, b};
        v2f res = cs * aa + nsc * bb;   // (c*a - s*b, s*a + c*b)
        v[r0]     = res.x;
        v[r0 + 1] = res.y;
    }
}

// strides 16,8,4,2,1 on half [B, B+32): wires c[0..4]/s[0..4]
template<int B>
__device__ __forceinline__ void ry5_half(float (&v)[64], const float* c, const float* s) {
    bfly_half<16, B>(v, c[0], s[0]);
    bfly_half<8,  B>(v, c[1], s[1]);
    bfly_half<4,  B>(v, c[2], s[2]);
    bfly_half<2,  B>(v, c[3], s[3]);
    bfly1_half<B>(v, c[4], s[4]);
}

// stride-32 butterfly across halves (applied last)
__device__ __forceinline__ void bfly32(float (&v)[64], float c, float s) {
    v2f c2 = {c, c}, s2 = {s, s};
    #pragma unroll
    for (int r0 = 0; r0 < 32; r0 += 2) {
        v2f a = {v[r0],      v[r0 + 1]};
        v2f b = {v[r0 + 32], v[r0 + 33]};
        v2f na = c2 * a - s2 * b;
        v2f nb = s2 * a + c2 * b;
        v[r0]      = na.x;  v[r0 + 1]  = na.y;
        v[r0 + 32] = nb.x;  v[r0 + 33] = nb.y;
    }
}

__global__ __launch_bounds__(64, 2)
void fwp_kernel(const float* __restrict__ x_t,
                const float* __restrict__ fast_prev,
                const float* __restrict__ W_enc,
                const float* __restrict__ b_enc,
                const float* __restrict__ W_upd,
                const float* __restrict__ b_upd,
                const float* __restrict__ W_ro,
                const float* __restrict__ b_ro,
                float* __restrict__ out_y,
                float* __restrict__ out_fast) {
    const int lane = threadIdx.x;   // block = one wave
    const int b    = blockIdx.x;

    __shared__ __align__(16) float s_xch[64 * PITCH];  // 16.9 KB transpose buffer
    __shared__ float s_c[FAST], s_s[FAST];             // per-gate cos/sin

    float* s_lat = s_xch;   // latent reuses the buffer (dead before layer 0)

    // ---- x row: wave-uniform address -> scalar loads, no broadcast needed ----
    const float* xrow = x_t + b * NQ;
    float xa[NQ];
    #pragma unroll
    for (int k = 0; k < NQ; k++) xa[k] = xrow[k];

    // ---- Phase A: latent = tanh(W_enc@x + b_enc), 8 per lane ----
    #pragma unroll
    for (int t = 0; t < LAT / 64; t++) {
        int j = lane + 64 * t;
        const float4* wr = (const float4*)(W_enc + j * NQ);
        float4 a0 = wr[0], a1 = wr[1], a2 = wr[2];
        float sum = b_enc[j]
            + a0.x * xa[0] + a0.y * xa[1] + a0.z * xa[2]  + a0.w * xa[3]
            + a1.x * xa[4] + a1.y * xa[5] + a1.z * xa[6]  + a1.w * xa[7]
            + a2.x * xa[8] + a2.y * xa[9] + a2.z * xa[10] + a2.w * xa[11];
        s_lat[j] = tanhf(sum);
    }
    // (no fence: in-order DS pipe + compiler alias analysis order the RAW)

    // ---- Phase B: 48 angles; lane o<48 owns one W_upd row; cos/sin to LDS ----
    if (lane < FAST) {
        const float4* wr = (const float4*)(W_upd + lane * LAT);
        const float4* lr = (const float4*)(s_lat);
        float sum = b_upd[lane];
        #pragma unroll 16
        for (int j = 0; j < LAT / 4; j++) {
            float4 w4 = wr[j];
            float4 l4 = lr[j];   // uniform address -> LDS broadcast
            sum += w4.x * l4.x + w4.y * l4.y + w4.z * l4.z + w4.w * l4.w;
        }
        float ang = DECAY * fast_prev[b * FAST + lane] + sum;
        out_fast[b * FAST + lane] = ang;
        float hh = 0.5f * ang;
        s_c[lane] = __cosf(hh);
        s_s[lane] = __sinf(hh);
    }

    // ---- closed-form product-state init (L orientation) ----
    float g0[NQ], g1[NQ];
    #pragma unroll
    for (int w = 0; w < NQ; w++) {
        float hh = 0.5f * xa[w];
        float c = __cosf(hh), s = __sinf(hh);
        g0[w] = (c - s) * 0.70710678118654752f;
        g1[w] = (c + s) * 0.70710678118654752f;
    }
    float L = 1.0f;
    #pragma unroll
    for (int w = 0; w < 6; w++)
        L *= ((lane >> (5 - w)) & 1) ? g1[w] : g0[w];

    float v[64];
    v[0] = L;
    #pragma unroll
    for (int w = 6; w < NQ; w++) {
        const int S = 1 << (11 - w);
        #pragma unroll
        for (int r = 0; r < 64; r += 2 * S) {
            v[r + S] = v[r] * g1[w];
            v[r]     = v[r] * g0[w];
        }
    }

    // Pass-1 read bases (verified r5/r7)
    const int A0 = ((lane ^ (lane >> 1)) & 31) | (lane & 32);
    const int A1 = A0 ^ 32;

    // ---- 4 layers, fully unrolled, zero fences ----
    #pragma unroll
    for (int layer = 0; layer < DEPTH; layer++) {
        float lc[NQ], ls[NQ];
        #pragma unroll
        for (int w = 0; w < NQ; w++) {
            lc[w] = s_c[layer * NQ + w];
            ls[w] = s_s[layer * NQ + w];
        }

        // -------- Pass 1: sigma + L->T folded into read addressing --------
        #pragma unroll
        for (int k = 0; k < 32; k++)
            *(v2f*)&s_xch[lane * PITCH + 2 * k] = (v2f){v[2 * k], v[2 * k + 1]};
        #pragma unroll
        for (int r = 0; r < 32; r++) {
            const int g = r ^ (r >> 1);
            v[r] = s_xch[g * PITCH + ((r & 1) ? A1 : A0)];
        }
        ry5_half<0>(v, lc + 1, ls + 1);      // wires 1..5 on lower half
        #pragma unroll
        for (int r = 32; r < 64; r++) {
            const int g = r ^ (r >> 1);
            v[r] = s_xch[g * PITCH + ((r & 1) ? A1 : A0)];
        }
        ry5_half<32>(v, lc + 1, ls + 1);     // wires 1..5 on upper half
        bfly32(v, lc[0], ls[0]);             // wire 0 last (commutes)

        // -------- Pass 2: plain transpose T->L --------
        #pragma unroll
        for (int k = 0; k < 32; k++)
            *(v2f*)&s_xch[lane * PITCH + 2 * k] = (v2f){v[2 * k], v[2 * k + 1]};
        #pragma unroll
        for (int r = 0; r < 32; r++) v[r] = s_xch[r * PITCH + lane];
        ry5_half<0>(v, lc + 7, ls + 7);      // wires 7..11 on lower half
        #pragma unroll
        for (int r = 32; r < 64; r++) v[r] = s_xch[r * PITCH + lane];
        ry5_half<32>(v, lc + 7, ls + 7);     // wires 7..11 on upper half
        bfly32(v, lc[6], ls[6]);             // wire 6 last (commutes)
    }

    // ---- Z expectations folded into readout (L orientation) ----
    float tot = 0.0f, pw[6] = {0, 0, 0, 0, 0, 0};
    #pragma unroll
    for (int r = 0; r < 64; r++) {
        float p = v[r] * v[r];
        tot += p;
        pw[0] += (r & 32) ? -p : p;   // wire 6
        pw[1] += (r & 16) ? -p : p;   // wire 7
        pw[2] += (r & 8)  ? -p : p;   // wire 8
        pw[3] += (r & 4)  ? -p : p;   // wire 9
        pw[4] += (r & 2)  ? -p : p;   // wire 10
        pw[5] += (r & 1)  ? -p : p;   // wire 11
    }
    float sl = 0.0f;
    #pragma unroll
    for (int w = 0; w < 6; w++) {
        float c = W_ro[w];
        sl += ((lane >> (5 - w)) & 1) ? -c : c;
    }
    float y = sl * tot;
    #pragma unroll
    for (int k = 0; k < 6; k++) y += W_ro[6 + k] * pw[k];
    #pragma unroll
    for (int m = 32; m >= 1; m >>= 1) y += __shfl_xor(y, m, 64);
    if (lane == 0) out_y[b] = y + b_ro[0];
}

extern "C" void kernel_launch(void* const* d_in, const int* in_sizes, int n_in,
                              void* d_out, int out_size, void* d_ws, size_t ws_size,
                              hipStream_t stream) {
    const float* x_t       = (const float*)d_in[0];
    const float* fast_prev = (const float*)d_in[1];
    const float* W_enc     = (const float*)d_in[2];
    const float* b_enc     = (const float*)d_in[3];
    const float* W_upd     = (const float*)d_in[4];
    const float* b_upd     = (const float*)d_in[5];
    const float* W_ro      = (const float*)d_in[6];
    const float* b_ro      = (const float*)d_in[7];
    float* out = (float*)d_out;

    fwp_kernel<<<2048, 64, 0, stream>>>(x_t, fast_prev, W_enc, b_enc,
                                        W_upd, b_upd, W_ro, b_ro,
                                        out /*y*/, out + 2048 /*fast_next*/);
}

// Round 9
// 108.299 us; speedup vs baseline: 1.0324x; 1.0324x over previous
//
#include <hip/hip_runtime.h>

// Problem constants
static constexpr int NQ    = 12;
static constexpr int DEPTH = 4;
static constexpr int LAT   = 512;
static constexpr int FAST  = DEPTH * NQ;   // 48
static constexpr float DECAY = 0.9f;
static constexpr int PITCH = 66;           // even (b64 writes), 2-way bank alias = free

using v2f = __attribute__((ext_vector_type(2))) float;

// ONE WAVE = TWO batch elements (A,B), 64 VGPRs of state each.
// L orientation: i = (lane<<6) | r  (wires 0..5 lane bits, 6..11 reg bits); T swaps.
// Layer = RY(12) ∘ CNOT-chain(0..10); sigma^-1: bit_p = j_p ^ j_{p+1}.
// Pass 1 folds sigma + L->T into LDS read addressing; pass 2 transposes back.
// A and B are software-pipelined through ONE buffer: the per-wave in-order DS
// pipe + conservative same-buffer aliasing order W/R bursts without fences
// (verified r8), so B's pass streams through the LDS pipe underneath A's
// butterflies and vice versa — the wave always has VALU work while DS drains.

template<int S, int B>
__device__ __forceinline__ void bfly_half(float (&v)[64], float c, float s) {
    v2f c2 = {c, c}, s2 = {s, s};
    #pragma unroll
    for (int r0 = B; r0 < B + 32; r0 += 2) {
        if ((r0 & S) == 0) {
            v2f a = {v[r0],     v[r0 + 1]};
            v2f b = {v[r0 + S], v[r0 + S + 1]};
            v2f na = c2 * a - s2 * b;
            v2f nb = s2 * a + c2 * b;
            v[r0]     = na.x;  v[r0 + 1]     = na.y;
            v[r0 + S] = nb.x;  v[r0 + S + 1] = nb.y;
        }
    }
}

template<int B>
__device__ __forceinline__ void bfly1_half(float (&v)[64], float c, float s) {
    v2f cs = {c, s}, nsc = {-s, c};
    #pragma unroll
    for (int r0 = B; r0 < B + 32; r0 += 2) {
        float a = v[r0], b = v[r0 + 1];
        v2f aa = {a, a}, bb = {b, b};
        v2f res = cs * aa + nsc * bb;   // (c*a - s*b, s*a + c*b)
        v[r0]     = res.x;
        v[r0 + 1] = res.y;
    }
}

// strides 16,8,4,2,1 on half [B,B+32): wires c[0..4]/s[0..4]
template<int B>
__device__ __forceinline__ void ry5_half(float (&v)[64], const float* c, const float* s) {
    bfly_half<16, B>(v, c[0], s[0]);
    bfly_half<8,  B>(v, c[1], s[1]);
    bfly_half<4,  B>(v, c[2], s[2]);
    bfly_half<2,  B>(v, c[3], s[3]);
    bfly1_half<B>(v, c[4], s[4]);
}

__device__ __forceinline__ void bfly32(float (&v)[64], float c, float s) {
    v2f c2 = {c, c}, s2 = {s, s};
    #pragma unroll
    for (int r0 = 0; r0 < 32; r0 += 2) {
        v2f a = {v[r0],      v[r0 + 1]};
        v2f b = {v[r0 + 32], v[r0 + 33]};
        v2f na = c2 * a - s2 * b;
        v2f nb = s2 * a + c2 * b;
        v[r0]      = na.x;  v[r0 + 1]  = na.y;
        v[r0 + 32] = nb.x;  v[r0 + 33] = nb.y;
    }
}

// transpose-buffer write: own row, b64
__device__ __forceinline__ void xw(const float (&v)[64], float* s_xch, int lane) {
    #pragma unroll
    for (int k = 0; k < 32; k++)
        *(v2f*)&s_xch[lane * PITCH + 2 * k] = (v2f){v[2 * k], v[2 * k + 1]};
}

// pass-1 read: sigma + L->T folded into addressing (verified r5/r7/r8)
__device__ __forceinline__ void p1r(float (&v)[64], const float* s_xch, int A0, int A1) {
    #pragma unroll
    for (int r = 0; r < 64; r++) {
        const int g = r ^ (r >> 1);
        v[r] = s_xch[g * PITCH + ((r & 1) ? A1 : A0)];
    }
}

// pass-2 read: plain transpose
__device__ __forceinline__ void p2r(float (&v)[64], const float* s_xch, int lane) {
    #pragma unroll
    for (int r = 0; r < 64; r++) v[r] = s_xch[r * PITCH + lane];
}

// closed-form product state from 12 initial RYs (verified r2..r8)
__device__ __forceinline__ void init_state(float (&v)[64], const float (&xa)[NQ], int lane) {
    float g0[NQ], g1[NQ];
    #pragma unroll
    for (int w = 0; w < NQ; w++) {
        float hh = 0.5f * xa[w];
        float c = __cosf(hh), s = __sinf(hh);
        g0[w] = (c - s) * 0.70710678118654752f;
        g1[w] = (c + s) * 0.70710678118654752f;
    }
    float L = 1.0f;
    #pragma unroll
    for (int w = 0; w < 6; w++)
        L *= ((lane >> (5 - w)) & 1) ? g1[w] : g0[w];
    v[0] = L;
    #pragma unroll
    for (int w = 6; w < NQ; w++) {
        const int S = 1 << (11 - w);
        #pragma unroll
        for (int r = 0; r < 64; r += 2 * S) {
            v[r + S] = v[r] * g1[w];
            v[r]     = v[r] * g0[w];
        }
    }
}

__global__ __launch_bounds__(64, 1)
void fwp_kernel(const float* __restrict__ x_t,
                const float* __restrict__ fast_prev,
                const float* __restrict__ W_enc,
                const float* __restrict__ b_enc,
                const float* __restrict__ W_upd,
                const float* __restrict__ b_upd,
                const float* __restrict__ W_ro,
                const float* __restrict__ b_ro,
                float* __restrict__ out_y,
                float* __restrict__ out_fast) {
    const int lane = threadIdx.x;          // block = one wave
    const int eA   = 2 * blockIdx.x;       // this wave's two batch elements
    const int eB   = eA + 1;

    __shared__ __align__(16) float s_xch[64 * PITCH];        // 16.9 KB, shared A/B
    __shared__ __align__(8)  float s_csA[2 * FAST], s_csB[2 * FAST]; // (cos,sin) pairs

    float* s_latA = s_xch;         // latent buffers carved from s_xch (dead later)
    float* s_latB = s_xch + LAT;

    // ---- x rows (wave-uniform scalar loads) ----
    float xaA[NQ], xaB[NQ];
    #pragma unroll
    for (int k = 0; k < NQ; k++) {
        xaA[k] = x_t[eA * NQ + k];
        xaB[k] = x_t[eB * NQ + k];
    }

    // ---- Phase A: latents for both elements; W_enc rows loaded once ----
    #pragma unroll
    for (int t = 0; t < LAT / 64; t++) {
        int j = lane + 64 * t;
        const float4* wr = (const float4*)(W_enc + j * NQ);
        float4 a0 = wr[0], a1 = wr[1], a2 = wr[2];
        float be = b_enc[j];
        float sA = be
            + a0.x * xaA[0] + a0.y * xaA[1] + a0.z * xaA[2]  + a0.w * xaA[3]
            + a1.x * xaA[4] + a1.y * xaA[5] + a1.z * xaA[6]  + a1.w * xaA[7]
            + a2.x * xaA[8] + a2.y * xaA[9] + a2.z * xaA[10] + a2.w * xaA[11];
        float sB = be
            + a0.x * xaB[0] + a0.y * xaB[1] + a0.z * xaB[2]  + a0.w * xaB[3]
            + a1.x * xaB[4] + a1.y * xaB[5] + a1.z * xaB[6]  + a1.w * xaB[7]
            + a2.x * xaB[8] + a2.y * xaB[9] + a2.z * xaB[10] + a2.w * xaB[11];
        s_latA[j] = tanhf(sA);
        s_latB[j] = tanhf(sB);
    }

    // ---- Phase B: 48 angles per element; W_upd row loaded once ----
    if (lane < FAST) {
        const float4* wr = (const float4*)(W_upd + lane * LAT);
        const float4* la = (const float4*)(s_latA);
        const float4* lb = (const float4*)(s_latB);
        float sA = b_upd[lane], sB = sA;
        #pragma unroll 8
        for (int j = 0; j < LAT / 4; j++) {
            float4 w4 = wr[j];
            float4 a4 = la[j];   // uniform -> LDS broadcast
            float4 b4 = lb[j];
            sA += w4.x * a4.x + w4.y * a4.y + w4.z * a4.z + w4.w * a4.w;
            sB += w4.x * b4.x + w4.y * b4.y + w4.z * b4.z + w4.w * b4.w;
        }
        float angA = DECAY * fast_prev[eA * FAST + lane] + sA;
        float angB = DECAY * fast_prev[eB * FAST + lane] + sB;
        out_fast[eA * FAST + lane] = angA;
        out_fast[eB * FAST + lane] = angB;
        *(v2f*)&s_csA[2 * lane] = (v2f){__cosf(0.5f * angA), __sinf(0.5f * angA)};
        *(v2f*)&s_csB[2 * lane] = (v2f){__cosf(0.5f * angB), __sinf(0.5f * angB)};
    }

    // ---- both product states ----
    float vA[64], vB[64];
    init_state(vA, xaA, lane);
    init_state(vB, xaB, lane);

    const int A0 = ((lane ^ (lane >> 1)) & 31) | (lane & 32);
    const int A1 = A0 ^ 32;

    // ---- 4 layers, A/B software-pipelined through one LDS buffer ----
    #pragma unroll 1   // keep body I-cache resident (~16 KB)
    for (int layer = 0; layer < DEPTH; layer++) {
        float lcA[NQ], lsA[NQ], lcB[NQ], lsB[NQ];
        #pragma unroll
        for (int w = 0; w < NQ; w++) {
            v2f ca = *(const v2f*)&s_csA[2 * (layer * NQ + w)];
            v2f cb = *(const v2f*)&s_csB[2 * (layer * NQ + w)];
            lcA[w] = ca.x;  lsA[w] = ca.y;
            lcB[w] = cb.x;  lsB[w] = cb.y;
        }

        // ---- pass 1 (sigma + L->T) ----
        xw(vA, s_xch, lane);
        p1r(vA, s_xch, A0, A1);
        xw(vB, s_xch, lane);                 // queues after vA reads (pipe order)
        ry5_half<0>(vA, lcA + 1, lsA + 1);   // waits only on writes -> fast
        p1r(vB, s_xch, A0, A1);              // streams under vA butterflies
        ry5_half<32>(vA, lcA + 1, lsA + 1);
        bfly32(vA, lcA[0], lsA[0]);          // wire 0
        ry5_half<0>(vB, lcB + 1, lsB + 1);

        // ---- pass 2 (plain transpose) ----
        xw(vA, s_xch, lane);                 // after vB p1 reads (pipe order)
        ry5_half<32>(vB, lcB + 1, lsB + 1);  // overlaps vA pass-2 writes
        bfly32(vB, lcB[0], lsB[0]);
        p2r(vA, s_xch, lane);
        xw(vB, s_xch, lane);
        ry5_half<0>(vA, lcA + 7, lsA + 7);
        p2r(vB, s_xch, lane);                // streams under vA butterflies
        ry5_half<32>(vA, lcA + 7, lsA + 7);
        bfly32(vA, lcA[6], lsA[6]);          // wire 6
        ry5_half<0>(vB, lcB + 7, lsB + 7);
        ry5_half<32>(vB, lcB + 7, lsB + 7);
        bfly32(vB, lcB[6], lsB[6]);
    }

    // ---- Z expectations folded into readout, both elements ----
    float wro[NQ];
    #pragma unroll
    for (int w = 0; w < NQ; w++) wro[w] = W_ro[w];
    float sl = 0.0f;                         // lane-sign dot: identical for A and B
    #pragma unroll
    for (int w = 0; w < 6; w++)
        sl += ((lane >> (5 - w)) & 1) ? -wro[w] : wro[w];

    float totA = 0.0f, pwA[6] = {0,0,0,0,0,0};
    float totB = 0.0f, pwB[6] = {0,0,0,0,0,0};
    #pragma unroll
    for (int r = 0; r < 64; r++) {
        float pA = vA[r] * vA[r];
        float pB = vB[r] * vB[r];
        totA += pA;  totB += pB;
        pwA[0] += (r & 32) ? -pA : pA;  pwB[0] += (r & 32) ? -pB : pB;
        pwA[1] += (r & 16) ? -pA : pA;  pwB[1] += (r & 16) ? -pB : pB;
        pwA[2] += (r & 8)  ? -pA : pA;  pwB[2] += (r & 8)  ? -pB : pB;
        pwA[3] += (r & 4)  ? -pA : pA;  pwB[3] += (r & 4)  ? -pB : pB;
        pwA[4] += (r & 2)  ? -pA : pA;  pwB[4] += (r & 2)  ? -pB : pB;
        pwA[5] += (r & 1)  ? -pA : pA;  pwB[5] += (r & 1)  ? -pB : pB;
    }
    float yA = sl * totA, yB = sl * totB;
    #pragma unroll
    for (int k = 0; k < 6; k++) {
        yA += wro[6 + k] * pwA[k];
        yB += wro[6 + k] * pwB[k];
    }
    #pragma unroll
    for (int m = 32; m >= 1; m >>= 1) {
        yA += __shfl_xor(yA, m, 64);
        yB += __shfl_xor(yB, m, 64);
    }
    if (lane == 0) {
        float br = b_ro[0];
        out_y[eA] = yA + br;
        out_y[eB] = yB + br;
    }
}

extern "C" void kernel_launch(void* const* d_in, const int* in_sizes, int n_in,
                              void* d_out, int out_size, void* d_ws, size_t ws_size,
                              hipStream_t stream) {
    const float* x_t       = (const float*)d_in[0];
    const float* fast_prev = (const float*)d_in[1];
    const float* W_enc     = (const float*)d_in[2];
    const float* b_enc     = (const float*)d_in[3];
    const float* W_upd     = (const float*)d_in[4];
    const float* b_upd     = (const float*)d_in[5];
    const float* W_ro      = (const float*)d_in[6];
    const float* b_ro      = (const float*)d_in[7];
    float* out = (float*)d_out;

    // 1024 blocks x 1 wave, 2 batch elements per wave
    fwp_kernel<<<1024, 64, 0, stream>>>(x_t, fast_prev, W_enc, b_enc,
                                        W_upd, b_upd, W_ro, b_ro,
                                        out /*y*/, out + 2048 /*fast_next*/);
}